// Round 9
// baseline (723.742 us; speedup 1.0000x reference)
//
#include <hip/hip_runtime.h>
#include <cstdint>
#include <cstddef>

#define TT 1000
#define NB 64000  // B*T

// ---------------------------------------------------------------------------
// NUMERICS CONTRACT (verified absmax 0.0 across sessions): each z[n,o] is
// ONE ascending-k fp32 fmaf chain; cuba is an exact per-t fp32 mul/add
// chain. Do not reorder, split, or tree-reduce. pk (f32x2) o-pair packing
// is exact.
//
// LEDGER:
//  dense r0/r1: 106-108us/gemm; busy 72us invariant; ~30% idle immovable
//    (occupancy r1, tile r2, counted-vmcnt r3/r4 all failed).
//  sparse r5-r7: DEAD (latency/select-bound, 148-300us).
//  r8 (mask+expand): cuba store was NOT the cost; gemms 102us unchanged.
//    => cuba (~190us total) is Z-READ-bound: 4B/lane stride-1KB loads,
//    1 wave/CU, ~3MB in flight = BDP wall (~1.3 TB/s on 64MB).
//  r9: gemm stores Z TRANSPOSED Zt[(b*O+o)*1000+t] (same 16 float4
//    stores/thread; 4-run t never crosses b since 4|1000); cuba reads its
//    own row contiguously via float4, depth-4 rotation (50 batches x 20t)
//    -> 4-8x bytes in flight, BW-bound. Mid-cuba keeps proven u8 scatter.
// ---------------------------------------------------------------------------

typedef __attribute__((ext_vector_type(2))) float f32x2;

// async global->LDS DMA: 16B/lane; LDS dest = wave-uniform base + lane*16;
// global src per-lane.
__device__ __forceinline__ void dma16(const void* g, void* l) {
  __builtin_amdgcn_global_load_lds(
      (const __attribute__((address_space(1))) unsigned int*)g,
      (__attribute__((address_space(3))) unsigned int*)l, 16, 0, 0);
}

// ---------------------------------------------------------------------------
// A image (DMA-ready): u32 idx = (n>>7)*(K/16)*512 + kt16*512 + kd*128
//   + (n&127); byte = k&3, kd = (k>>2)&3.
// W: plain transposed [K][Opad] f32.
// Zt: [(b*O + o)][t] f32 (gemm writes transposed; cuba reads contiguous).
// ---------------------------------------------------------------------------

// ---------------------------------------------------------------------------
// gemm_dma BK=32 (r1 core, proven 102-108us): 128n x 128o block, 256 thr,
// 8x8/thread (pk f32x2). Double-buffered LDS (40 KB), ONE barrier per
// 32-k tile. Epilogue: TRANSPOSED float4 stores into Zt.
// ---------------------------------------------------------------------------
__global__ __launch_bounds__(256) void gemm_dma(
    const unsigned int* __restrict__ Aswz, const float* __restrict__ Wt,
    float* __restrict__ Zt, int KT32, int Wld, int Od) {
  __shared__ unsigned int AsU[2][1024];        // 32k x 128row packed u8
  __shared__ __align__(16) float Bs[2][4096];  // 32k x 128o
  const int t = threadIdx.x;
  const int lane = t & 63;
  const int wave = t >> 6;
  const int bn = blockIdx.x * 128;
  const int bo = blockIdx.y * 128;
  const int tx4 = (t & 15) * 4;
  const int ty4 = ((t >> 4) & 15) * 4;

  // B DMA geometry: wave covers rows 2w..2w+1 (+8d per dma d)
  const int f0 = wave * 64 + lane;
  const int bk0 = f0 >> 5;
  const int bc0 = (f0 & 31) * 4;
  const float* wsrc = Wt + (size_t)bk0 * Wld + bo + bc0;
  // A DMA: 4 waves x 256 dwords = 1024 dwords (one 32-k tile)
  const unsigned int* asrc =
      Aswz + (size_t)blockIdx.x * KT32 * 1024 + wave * 256 + lane * 4;

  f32x2 acc[8][4];
#pragma unroll
  for (int j = 0; j < 8; j++)
#pragma unroll
    for (int i = 0; i < 4; i++) {
      acc[j][i][0] = 0.f;
      acc[j][i][1] = 0.f;
    }

  // prologue: stage tile 0
#pragma unroll
  for (int d = 0; d < 4; d++)
    dma16(wsrc + (size_t)(8 * d) * Wld, &Bs[0][1024 * d + wave * 256]);
  dma16(asrc, &AsU[0][wave * 256]);
  __syncthreads();

  for (int tile = 0; tile < KT32; tile++) {
    const int cur = tile & 1, nxt = cur ^ 1;
    if (tile + 1 < KT32) {  // zero-VGPR async prefetch, lands during compute
      const float* wn = wsrc + (size_t)(tile + 1) * 32 * Wld;
#pragma unroll
      for (int d = 0; d < 4; d++)
        dma16(wn + (size_t)(8 * d) * Wld, &Bs[nxt][1024 * d + wave * 256]);
      dma16(asrc + (size_t)(tile + 1) * 1024, &AsU[nxt][wave * 256]);
    }
#pragma unroll
    for (int kh = 0; kh < 2; kh++) {
#pragma unroll
      for (int kq = 0; kq < 4; kq++) {
        uint4 a0 = *(const uint4*)&AsU[cur][kh * 512 + kq * 128 + ty4];
        uint4 a1 = *(const uint4*)&AsU[cur][kh * 512 + kq * 128 + 64 + ty4];
#pragma unroll
        for (int k2 = 0; k2 < 4; k2++) {
          const int kk = kh * 16 + kq * 4 + k2;
          const int sh = k2 * 8;
          float av[8];
          av[0] = (float)((a0.x >> sh) & 0xffu);  // v_cvt_f32_ubyte
          av[1] = (float)((a0.y >> sh) & 0xffu);
          av[2] = (float)((a0.z >> sh) & 0xffu);
          av[3] = (float)((a0.w >> sh) & 0xffu);
          av[4] = (float)((a1.x >> sh) & 0xffu);
          av[5] = (float)((a1.y >> sh) & 0xffu);
          av[6] = (float)((a1.z >> sh) & 0xffu);
          av[7] = (float)((a1.w >> sh) & 0xffu);
          float4 b0 = *(const float4*)&Bs[cur][kk * 128 + tx4];
          float4 b1 = *(const float4*)&Bs[cur][kk * 128 + 64 + tx4];
          f32x2 bp[4];
          bp[0][0] = b0.x; bp[0][1] = b0.y;
          bp[1][0] = b0.z; bp[1][1] = b0.w;
          bp[2][0] = b1.x; bp[2][1] = b1.y;
          bp[3][0] = b1.z; bp[3][1] = b1.w;
#pragma unroll
          for (int j = 0; j < 8; j++) {
            f32x2 a2;
            a2[0] = av[j];
            a2[1] = av[j];
#pragma unroll
            for (int i = 0; i < 4; i++)
              acc[j][i] = __builtin_elementwise_fma(a2, bp[i], acc[j][i]);
          }
        }
      }
    }
    __syncthreads();
  }

  // transposed epilogue: per jp a 4-run of consecutive n = consecutive t
  // of ONE b (n0 is 4-aligned and 4 | 1000 => never crosses b).
#pragma unroll
  for (int jp = 0; jp < 2; jp++) {
    int n0 = bn + jp * 64 + ty4;
    int b = n0 / 1000;
    int t0 = n0 - b * 1000;
    float* zb = Zt + (size_t)b * Od * 1000 + t0;
#pragma unroll
    for (int i = 0; i < 4; i++) {
#pragma unroll
      for (int s = 0; s < 2; s++) {
        int o = bo + (i >> 1) * 64 + tx4 + (i & 1) * 2 + s;
        float4 v = make_float4(acc[jp * 4 + 0][i][s], acc[jp * 4 + 1][i][s],
                               acc[jp * 4 + 2][i][s], acc[jp * 4 + 3][i][s]);
        *(float4*)&zb[(size_t)o * 1000] = v;
      }
    }
  }
}

// ---------------------------------------------------------------------------
// gemm_l4: layer 4, O=35 padded 64. 256n x 64o block, BK=16. Transposed
// epilogue into Zt rows (b*35+o); 8-run of t never crosses b (8 | 1000).
// ---------------------------------------------------------------------------
__global__ __launch_bounds__(256) void gemm_l4(
    const unsigned int* __restrict__ Aswz, const float* __restrict__ Wt,
    float* __restrict__ Zt) {
  const int KT = 16, OS = 35;
  __shared__ unsigned int Al[2][1024];
  __shared__ __align__(16) float Bl[2][1024];
  const int t = threadIdx.x;
  const int lane = t & 63;
  const int wave = t >> 6;
  const int bn = blockIdx.x * 256;
  const int h = wave >> 1;
  const int ny = (lane >> 3) * 8;
  const int ox = (lane & 7) * 8;
  const int lrow = (wave & 1) * 64 + ny;

  const unsigned int* asrc = Aswz +
      (size_t)(blockIdx.x * 2 + (wave >> 1)) * KT * 512 + (wave & 1) * 256 +
      lane * 4;
  const float* wsrc = Wt + wave * 256 + lane * 4;

  f32x2 acc[8][4];
#pragma unroll
  for (int j = 0; j < 8; j++)
#pragma unroll
    for (int i = 0; i < 4; i++) {
      acc[j][i][0] = 0.f;
      acc[j][i][1] = 0.f;
    }

  dma16(asrc, &Al[0][wave * 256]);
  dma16(wsrc, &Bl[0][wave * 256]);
  __syncthreads();

  for (int tile = 0; tile < KT; tile++) {
    const int cur = tile & 1, nxt = cur ^ 1;
    if (tile + 1 < KT) {
      dma16(asrc + (size_t)(tile + 1) * 512, &Al[nxt][wave * 256]);
      dma16(wsrc + (size_t)(tile + 1) * 1024, &Bl[nxt][wave * 256]);
    }
#pragma unroll
    for (int kq = 0; kq < 4; kq++) {
      uint4 a0 = *(const uint4*)&Al[cur][h * 512 + kq * 128 + lrow];
      uint4 a1 = *(const uint4*)&Al[cur][h * 512 + kq * 128 + lrow + 4];
#pragma unroll
      for (int k2 = 0; k2 < 4; k2++) {
        const int kk = kq * 4 + k2;
        const int sh = k2 * 8;
        float av[8];
        av[0] = (float)((a0.x >> sh) & 0xffu);
        av[1] = (float)((a0.y >> sh) & 0xffu);
        av[2] = (float)((a0.z >> sh) & 0xffu);
        av[3] = (float)((a0.w >> sh) & 0xffu);
        av[4] = (float)((a1.x >> sh) & 0xffu);
        av[5] = (float)((a1.y >> sh) & 0xffu);
        av[6] = (float)((a1.z >> sh) & 0xffu);
        av[7] = (float)((a1.w >> sh) & 0xffu);
        float4 b0 = *(const float4*)&Bl[cur][kk * 64 + ox];
        float4 b1 = *(const float4*)&Bl[cur][kk * 64 + ox + 4];
        f32x2 bp[4];
        bp[0][0] = b0.x; bp[0][1] = b0.y;
        bp[1][0] = b0.z; bp[1][1] = b0.w;
        bp[2][0] = b1.x; bp[2][1] = b1.y;
        bp[3][0] = b1.z; bp[3][1] = b1.w;
#pragma unroll
        for (int j = 0; j < 8; j++) {
          f32x2 a2;
          a2[0] = av[j];
          a2[1] = av[j];
#pragma unroll
          for (int i = 0; i < 4; i++)
            acc[j][i] = __builtin_elementwise_fma(a2, bp[i], acc[j][i]);
        }
      }
    }
    __syncthreads();
  }

  {
    int n0 = bn + wave * 64 + ny;  // 8-aligned; 8 | 1000 => one b
    int b = n0 / 1000;
    int t0 = n0 - b * 1000;
#pragma unroll
    for (int i = 0; i < 4; i++) {
#pragma unroll
      for (int s = 0; s < 2; s++) {
        int o = ox + i * 2 + s;
        if (o < OS) {
          float* zb = Zt + ((size_t)b * OS + o) * 1000 + t0;
          *(float4*)zb =
              make_float4(acc[0][i][s], acc[1][i][s], acc[2][i][s],
                          acc[3][i][s]);
          *(float4*)(zb + 4) =
              make_float4(acc[4][i][s], acc[5][i][s], acc[6][i][s],
                          acc[7][i][s]);
        }
      }
    }
  }
}

// ---------------------------------------------------------------------------
// CUBA LIF recurrence: each thread owns row gid = b*O+o of Zt, read
// CONTIGUOUSLY via float4, depth-4 rotation (50 batches x 20 t, prefetch
// 3 batches ahead = 15 float4 in flight). Exact per-step fp32 chain,
// ascending t. Mid layers: r1-proven u8 scatter store into A-image.
// Final: batched float4 spike stores.
// ---------------------------------------------------------------------------
template <bool FINAL>
__global__ __launch_bounds__(64) void cuba_kernel(
    const float* __restrict__ Zt, uint8_t* __restrict__ Sout,
    float* __restrict__ Fout, unsigned int* __restrict__ cnt, int O,
    int total) {
  int gid = blockIdx.x * 64 + threadIdx.x;
  unsigned int c = 0;
  if (gid < total) {
    int b = gid / O;
    int o = gid - b * O;
    const float* zp = Zt + (size_t)gid * TT;
    float* fp = Fout + (size_t)gid * TT;
    const int koff = (o >> 4) * 2048 + ((o >> 2) & 3) * 512 + (o & 3);
    float cur = 0.f, volt = 0.f;
    float4 q[4][5];

    // prologue: batches 0,1,2
#pragma unroll
    for (int pb = 0; pb < 3; pb++)
#pragma unroll
      for (int u = 0; u < 5; u++)
        q[pb][u] = *(const float4*)&zp[pb * 20 + u * 4];

#pragma unroll
    for (int cb = 0; cb < 50; cb++) {
      if (cb + 3 < 50) {  // compile-time per unrolled iteration
#pragma unroll
        for (int u = 0; u < 5; u++)
          q[(cb + 3) & 3][u] = *(const float4*)&zp[(cb + 3) * 20 + u * 4];
      }
#pragma unroll
      for (int u = 0; u < 5; u++) {
        float4 zq = q[cb & 3][u];
        float4 fv;
#pragma unroll
        for (int v = 0; v < 4; v++) {
          float z = (v == 0) ? zq.x : (v == 1) ? zq.y : (v == 2) ? zq.z
                                                                 : zq.w;
          cur = __fadd_rn(__fmul_rn(0.75f, cur), z);
          volt = __fadd_rn(__fmul_rn(0.97f, volt), cur);
          bool fire = volt >= 1.25f;
          volt = fire ? 0.f : volt;
          c += fire ? 1u : 0u;
          float fs = fire ? 1.f : 0.f;
          if (v == 0) fv.x = fs;
          if (v == 1) fv.y = fs;
          if (v == 2) fv.z = fs;
          if (v == 3) fv.w = fs;
          if (!FINAL) {
            int n = b * TT + cb * 20 + u * 4 + v;
            Sout[(size_t)(n >> 7) * 32768 + koff + ((n & 127) << 2)] =
                (uint8_t)(fire ? 1 : 0);
          }
        }
        if (FINAL) {
          *(float4*)&fp[cb * 20 + u * 4] = fv;
        }
      }
    }
  }
#pragma unroll
  for (int off = 32; off; off >>= 1) c += __shfl_down(c, off, 64);
  if ((threadIdx.x & 63) == 0) atomicAdd(cnt, c);
}

// ---------------------------------------------------------------------------
// Fused prep (r1, proven): cnt zero + input u8 image (K=32 padded) + 4
// weight transposes.
// ---------------------------------------------------------------------------
__device__ __forceinline__ void prep_w_item(const float* __restrict__ W,
                                            float* __restrict__ Wt, int O,
                                            int K, int Opad, int i) {
  int k = i / Opad, o = i - k * Opad;
  Wt[i] = (k < K && o < O) ? W[(size_t)o * K + k] : 0.f;
}

__global__ __launch_bounds__(256) void prep_all(
    const float* __restrict__ X, const float* __restrict__ W1,
    const float* __restrict__ W2, const float* __restrict__ W3,
    const float* __restrict__ W4, unsigned int* __restrict__ Ain,
    float* __restrict__ Wt1, float* __restrict__ Wt2,
    float* __restrict__ Wt3, float* __restrict__ Wt4,
    unsigned int* __restrict__ cnt) {
  const int blk = blockIdx.x;
  const int tid = threadIdx.x;
  if (blk == 0 && tid < 8) cnt[tid] = 0u;
  if (blk < 250) {
    int gid = blk * 256 + tid;  // n
    unsigned int w[8];
#pragma unroll
    for (int i = 0; i < 8; i++) w[i] = 0u;
#pragma unroll
    for (int c = 0; c < 20; c++) {
      float v = X[((size_t)(gid / TT) * 20 + c) * TT + (gid % TT)];
      w[c >> 2] |= (v != 0.f ? 1u : 0u) << ((c & 3) * 8);
    }
    // A image (K=32): idx = (n>>7)*1024 + k16*512 + kd*128 + (n&127)
    unsigned int base = (gid >> 7) * 1024 + (gid & 127);
#pragma unroll
    for (int kd8 = 0; kd8 < 8; kd8++)
      Ain[base + (kd8 >> 2) * 512 + (kd8 & 3) * 128] = w[kd8];
  } else if (blk < 282) {
    prep_w_item(W1, Wt1, 256, 20, 256, (blk - 250) * 256 + tid);
  } else if (blk < 538) {
    prep_w_item(W2, Wt2, 256, 256, 256, (blk - 282) * 256 + tid);
  } else if (blk < 794) {
    prep_w_item(W3, Wt3, 256, 256, 256, (blk - 538) * 256 + tid);
  } else {
    prep_w_item(W4, Wt4, 35, 256, 64, (blk - 794) * 256 + tid);
  }
}

__global__ void finalize_counts(const unsigned int* __restrict__ cnt,
                                float* __restrict__ out) {
  int i = threadIdx.x;
  if (i < 4) {
    const float denom[4] = {16384000.f, 16384000.f, 16384000.f, 2240000.f};
    out[i] = (float)cnt[i] / denom[i];
  }
}

// ---------------------------------------------------------------------------
extern "C" void kernel_launch(void* const* d_in, const int* in_sizes, int n_in,
                              void* d_out, int out_size, void* d_ws,
                              size_t ws_size, hipStream_t stream) {
  const float* X = (const float*)d_in[0];
  const float* W1 = (const float*)d_in[1];
  const float* W2 = (const float*)d_in[2];
  const float* W3 = (const float*)d_in[3];
  const float* W4 = (const float*)d_in[4];
  float* out = (float*)d_out;

  char* ws = (char*)d_ws;
  unsigned int* cnt = (unsigned int*)ws;                       // 256 B
  float* Z = (float*)(ws + 256);                               // 65,536,000
  unsigned int* Sa = (unsigned int*)(ws + 256 + 65536000ull);  // 16,384,000
  unsigned int* Sb = Sa + 4096000ull;                          // 16,384,000
  unsigned int* Sin = Sb + 4096000ull;                         // 2,048,000
  float* Wt1 = (float*)(Sin + 512000ull);                      // 8192 f
  float* Wt2 = Wt1 + 8192;                                     // 65536 f
  float* Wt3 = Wt2 + 65536;                                    // 65536 f
  float* Wt4 = Wt3 + 65536;                                    // 16384 f

  prep_all<<<858, 256, 0, stream>>>(X, W1, W2, W3, W4, Sin, Wt1, Wt2, Wt3,
                                    Wt4, cnt);

  dim3 gBig(500, 2);

  gemm_dma<<<gBig, 256, 0, stream>>>(Sin, Wt1, Z, 1, 256, 256);
  cuba_kernel<false><<<256, 64, 0, stream>>>(Z, (uint8_t*)Sa, nullptr, cnt + 0,
                                             256, 16384);
  gemm_dma<<<gBig, 256, 0, stream>>>(Sa, Wt2, Z, 8, 256, 256);
  cuba_kernel<false><<<256, 64, 0, stream>>>(Z, (uint8_t*)Sb, nullptr, cnt + 1,
                                             256, 16384);
  gemm_dma<<<gBig, 256, 0, stream>>>(Sb, Wt3, Z, 8, 256, 256);
  cuba_kernel<false><<<256, 64, 0, stream>>>(Z, (uint8_t*)Sa, nullptr, cnt + 2,
                                             256, 16384);
  gemm_l4<<<250, 256, 0, stream>>>(Sa, Wt4, Z);
  cuba_kernel<true><<<35, 64, 0, stream>>>(Z, nullptr, out, cnt + 3, 35, 2240);
  finalize_counts<<<1, 64, 0, stream>>>(cnt, out + 2240000);
}